// Round 8
// baseline (438.694 us; speedup 1.0000x reference)
//
#include <hip/hip_runtime.h>

// B=2, L=2048, C=1024, H=16, D=64.
// [k_convert]   fp32 -> bf16: Xb (linear), Wb (q/k rows permuted so each head's
//               cols are [even-d | odd-d]), Wpb (linear).
// [k_gemm_qkv]  bf16 MFMA GEMM (M=4096,N=3072,K=1024), 128x128 tile, BK=32,
//               global_load_lds staging; epilogue: in-lane RoPE for q/k
//               -> [b][h][l][64]; q-scale has log2(e) folded in (softmax runs
//               in base-2); V stored TRANSPOSED vt[b][h][d][l].
// [k_attn]      flash attention, KVBLK=128. Register-prefetch of next tile's
//               K-frags + V-regs (ping-pong, overlaps full iteration);
//               double-buffered Vt LDS; ONE raw s_barrier per iter with
//               lgkmcnt(0)-only wait (prefetch loads stay in flight across
//               the barrier); DPP softmax, base-2 exp.
// [k_gemm_proj] bf16 MFMA GEMM (M=4096,N=1024,K=1024) + bias, fp32 out.

typedef __attribute__((ext_vector_type(8))) short s8v;            // 8 x bf16
typedef __attribute__((ext_vector_type(4))) float f4v;            // 4 x f32
typedef __attribute__((ext_vector_type(4))) unsigned short u16x4; // 4 x bf16

__device__ __forceinline__ unsigned short f2bf(float f) {
  unsigned int u = __float_as_uint(f);
  u += 0x7FFFu + ((u >> 16) & 1u);   // RNE
  return (unsigned short)(u >> 16);
}

__device__ __forceinline__ void gl16(const unsigned short* g, unsigned short* l) {
  __builtin_amdgcn_global_load_lds((const __attribute__((address_space(1))) void*)g,
                                   (__attribute__((address_space(3))) void*)l,
                                   16, 0, 0);
}

__device__ __forceinline__ s8v pack8(const float* p) {
  const float4 a = *reinterpret_cast<const float4*>(p);
  const float4 b = *reinterpret_cast<const float4*>(p + 4);
  s8v r;
  r[0]=(short)f2bf(a.x); r[1]=(short)f2bf(a.y); r[2]=(short)f2bf(a.z); r[3]=(short)f2bf(a.w);
  r[4]=(short)f2bf(b.x); r[5]=(short)f2bf(b.y); r[6]=(short)f2bf(b.z); r[7]=(short)f2bf(b.w);
  return r;
}

// DPP lane permute within rows of 16 (VALU-speed, no LDS pipe).
#define DPP_F(x, ctrl) \
  __int_as_float(__builtin_amdgcn_update_dpp(0, __float_as_int(x), (ctrl), 0xf, 0xf, false))

__device__ __forceinline__ float row16_max(float x) {
  x = fmaxf(x, DPP_F(x, 0xB1));
  x = fmaxf(x, DPP_F(x, 0x4E));
  x = fmaxf(x, DPP_F(x, 0x124));
  x = fmaxf(x, DPP_F(x, 0x128));
  return x;
}
__device__ __forceinline__ float row16_sum(float x) {
  x += DPP_F(x, 0xB1);
  x += DPP_F(x, 0x4E);
  x += DPP_F(x, 0x124);
  x += DPP_F(x, 0x128);
  return x;
}

// ---------------------------------------------------------------------------
// Convert: blocks [0,2048) X (4M), [2048,3584) W (3M, q/k rows permuted),
//          [3584,4096) Wp (1M). 8 floats per thread.
// ---------------------------------------------------------------------------
__global__ __launch_bounds__(256)
void k_convert(const float* __restrict__ X, const float* __restrict__ W,
               const float* __restrict__ Wp,
               unsigned short* __restrict__ Xb, unsigned short* __restrict__ Wb,
               unsigned short* __restrict__ Wpb)
{
  const int bid = blockIdx.x, tid = threadIdx.x;
  if (bid < 2048) {
    const size_t e = (size_t)bid * 2048 + (size_t)tid * 8;
    *reinterpret_cast<s8v*>(Xb + e) = pack8(X + e);
  } else if (bid < 3584) {
    const size_t e = (size_t)(bid - 2048) * 2048 + (size_t)tid * 8;
    const int p = (int)(e >> 10);          // dst row
    const int col = (int)(e & 1023);
    int n;                                  // src row
    if (p < 2048) {                         // q/k: de-interleave head dims
      const int t = p >> 10;
      const int hh = (p & 1023) >> 6;
      const int c = p & 63;
      const int d = (c < 32) ? (c << 1) : (((c - 32) << 1) | 1);
      n = (t << 10) + (hh << 6) + d;
    } else {
      n = p;                                // v: identity
    }
    *reinterpret_cast<s8v*>(Wb + e) = pack8(W + (size_t)n * 1024 + col);
  } else {
    const size_t e = (size_t)(bid - 3584) * 2048 + (size_t)tid * 8;
    *reinterpret_cast<s8v*>(Wpb + e) = pack8(Wp + e);
  }
}

// ---------------------------------------------------------------------------
// GEMM1 (MFMA): qkv = Xb @ Wb^T, fused RoPE/scale epilogue.
// q/k -> bf16 [b][h][l][64] (permuted-d layout); v -> TRANSPOSED vt[b][h][d][l].
// q-scale = 1/sqrt(64) * log2(e)  (softmax computed in base-2 downstream).
// ---------------------------------------------------------------------------
__global__ __launch_bounds__(256)
void k_gemm_qkv(const unsigned short* __restrict__ Ab,   // [4096][1024]
                const unsigned short* __restrict__ Bb,   // [3072][1024] permuted
                const float* __restrict__ Ct, const float* __restrict__ St,
                unsigned short* __restrict__ qb, unsigned short* __restrict__ kb,
                unsigned short* __restrict__ vt)
{
  __shared__ __align__(16) unsigned short Asm[128 * 32];
  __shared__ __align__(16) unsigned short Bsm[128 * 32];

  const int tid  = threadIdx.x;
  const int w    = tid >> 6;
  const int lane = tid & 63;
  const int lr   = lane & 15;
  const int lg   = lane >> 4;
  const int wm   = w >> 1, wn = w & 1;

  const int row0 = blockIdx.x << 7;
  const int col0 = blockIdx.y << 7;

  const int srow = (w << 5) + (lane >> 2);
  const int scol = (lane & 3) << 3;
  const unsigned short* Ag = Ab + (size_t)(row0 + srow) * 1024 + scol;
  const unsigned short* Bg = Bb + (size_t)(col0 + srow) * 1024 + scol;
  unsigned short* Al0 = &Asm[(w << 5) * 32];
  unsigned short* Al1 = Al0 + 512;
  unsigned short* Bl0 = &Bsm[(w << 5) * 32];
  unsigned short* Bl1 = Bl0 + 512;

  f4v acc[4][4];
#pragma unroll
  for (int m = 0; m < 4; ++m)
#pragma unroll
    for (int n = 0; n < 4; ++n) acc[m][n] = (f4v){0.f, 0.f, 0.f, 0.f};

  for (int k0 = 0; k0 < 1024; k0 += 32) {
    gl16(Ag + k0, Al0);
    gl16(Ag + k0 + 16 * 1024, Al1);
    gl16(Bg + k0, Bl0);
    gl16(Bg + k0 + 16 * 1024, Bl1);
    __syncthreads();

    s8v af[4], bfr[4];
#pragma unroll
    for (int m = 0; m < 4; ++m)
      af[m] = *reinterpret_cast<const s8v*>(&Asm[(wm * 64 + m * 16 + lr) * 32 + lg * 8]);
#pragma unroll
    for (int n = 0; n < 4; ++n)
      bfr[n] = *reinterpret_cast<const s8v*>(&Bsm[(wn * 64 + n * 16 + lr) * 32 + lg * 8]);
#pragma unroll
    for (int m = 0; m < 4; ++m)
#pragma unroll
      for (int n = 0; n < 4; ++n)
        acc[m][n] = __builtin_amdgcn_mfma_f32_16x16x32_bf16(af[m], bfr[n], acc[m][n], 0, 0, 0);
    __syncthreads();
  }

  const int colbase = col0 + wn * 64;
  const int t  = colbase >> 10;
  const int h  = (colbase & 1023) >> 6;

  if (t == 2) {
    // V: transposed store vt[b][h][d][l], 4 consecutive tokens packed per 8B.
#pragma unroll
    for (int m = 0; m < 4; ++m) {
      const int token = row0 + wm * 64 + m * 16 + lg * 4;
      const int bI = token >> 11;
      const int lI = token & 2047;
      unsigned short* vbase = vt + (((size_t)bI * 16 + h) * 64) * 2048 + lI;
#pragma unroll
      for (int n = 0; n < 4; ++n) {
        const int d = n * 16 + lr;
        u16x4 pk;
        pk[0] = f2bf(acc[m][n][0]); pk[1] = f2bf(acc[m][n][1]);
        pk[2] = f2bf(acc[m][n][2]); pk[3] = f2bf(acc[m][n][3]);
        *reinterpret_cast<u16x4*>(vbase + (size_t)d * 2048) = pk;
      }
    }
  } else {
    unsigned short* dst = (t == 0) ? qb : kb;
    // 0.125 * log2(e): softmax uses exp2 downstream
    const float sc = (t == 0) ? 0.18033688011112042f : 1.0f;
#pragma unroll
    for (int m = 0; m < 4; ++m) {
#pragma unroll
      for (int j = 0; j < 4; ++j) {
        const int token = row0 + wm * 64 + m * 16 + lg * 4 + j;
        const int bI = token >> 11;
        const int lI = token & 2047;
        unsigned short* rowp = dst + (((size_t)bI * 16 + h) * 2048 + lI) * 64;
#pragma unroll
        for (int pn = 0; pn < 2; ++pn) {
          const int d2 = pn * 16 + lr;
          const float c = Ct[lI * 32 + d2];
          const float s = St[lI * 32 + d2];
          const float e = acc[m][pn][j];
          const float o = acc[m][pn + 2][j];
          rowp[d2]      = f2bf((e * c - o * s) * sc);
          rowp[32 + d2] = f2bf((e * s + o * c) * sc);
        }
      }
    }
  }
}

// ---------------------------------------------------------------------------
// Flash attention: 4 waves, wave w owns 16 q-rows; KVBLK=128.
// Register-prefetch (ping-pong) of next tile's K frags + V regs; Vt double-
// buffered in LDS; one raw s_barrier/iter with lgkmcnt-only wait so prefetch
// global loads stay in flight across the barrier.
// ---------------------------------------------------------------------------
__global__ __launch_bounds__(256)
void k_attn(const unsigned short* __restrict__ qb,
            const unsigned short* __restrict__ kb,
            const unsigned short* __restrict__ vt,
            unsigned short* __restrict__ ab)
{
  __shared__ unsigned short Ps[4][16][132];   // per-wave P tile (16 q x 128 k)
  __shared__ unsigned short Vt0[64][132];     // V^T tile double-buffer
  __shared__ unsigned short Vt1[64][132];

  const int tid  = threadIdx.x;
  const int w    = tid >> 6;
  const int lane = tid & 63;
  const int lr   = lane & 15;
  const int lg   = lane >> 4;

  const int bx = blockIdx.x;
  const int qt = bx & 31;
  const int h  = (bx >> 5) & 15;
  const int b  = bx >> 9;

  const size_t bh = ((size_t)b * 16 + h) * 2048;
  const unsigned short* Qp  = qb + (bh + (size_t)qt * 64 + w * 16) * 64;
  const unsigned short* Kp  = kb + bh * 64;
  const unsigned short* Vg  = vt + bh * 64;   // [d][l] for this (b,h)

  const s8v qa0 = *reinterpret_cast<const s8v*>(Qp + lr * 64 + 0 + lg * 8);
  const s8v qa1 = *reinterpret_cast<const s8v*>(Qp + lr * 64 + 32 + lg * 8);

  f4v o[4];
#pragma unroll
  for (int i = 0; i < 4; ++i) o[i] = (f4v){0.f, 0.f, 0.f, 0.f};
  float mrow[4] = {-1e30f, -1e30f, -1e30f, -1e30f};
  float lrow[4] = {0.f, 0.f, 0.f, 0.f};

  // V staging: thread covers 64B of row sd: shorts [sk + j*32, +8) j=0..3
  const int sd = tid >> 2;             // d row 0..63
  const int sk = (tid & 3) << 3;       // 0,8,16,24 shorts

  s8v kfA[8][2], kfB[8][2], vvA[4], vvB[4];

  auto LOAD = [&](s8v (&kf)[8][2], s8v (&vv)[4], int t) {
    const unsigned short* Kt = Kp + (size_t)t * 128 * 64;
    const unsigned short* vs = Vg + (size_t)sd * 2048 + t * 128 + sk;
#pragma unroll
    for (int j = 0; j < 4; ++j)
      vv[j] = *reinterpret_cast<const s8v*>(vs + j * 32);
#pragma unroll
    for (int ct = 0; ct < 8; ++ct) {
      kf[ct][0] = *reinterpret_cast<const s8v*>(Kt + (ct * 16 + lr) * 64 + 0 + lg * 8);
      kf[ct][1] = *reinterpret_cast<const s8v*>(Kt + (ct * 16 + lr) * 64 + 32 + lg * 8);
    }
  };

  auto ITER = [&](s8v (&kf)[8][2], s8v (&vv)[4], unsigned short (*VT)[132]) {
    // stage V tile (straight contiguous copy, conflict-free b128)
#pragma unroll
    for (int j = 0; j < 4; ++j)
      *reinterpret_cast<s8v*>(&VT[sd][sk + j * 32]) = vv[j];

    // S = q . K^T over 128 keys (8 column-tiles of 16); base-2 logits
    f4v s[8];
#pragma unroll
    for (int ct = 0; ct < 8; ++ct) {
      f4v z = (f4v){0.f, 0.f, 0.f, 0.f};
      z = __builtin_amdgcn_mfma_f32_16x16x32_bf16(qa0, kf[ct][0], z, 0, 0, 0);
      z = __builtin_amdgcn_mfma_f32_16x16x32_bf16(qa1, kf[ct][1], z, 0, 0, 0);
      s[ct] = z;
    }

    // online softmax (base-2), DPP row-reduces; P -> wave-private LDS
#pragma unroll
    for (int r = 0; r < 4; ++r) {
      float mx = fmaxf(fmaxf(fmaxf(s[0][r], s[1][r]), fmaxf(s[2][r], s[3][r])),
                       fmaxf(fmaxf(s[4][r], s[5][r]), fmaxf(s[6][r], s[7][r])));
      mx = row16_max(mx);
      const float mnew = fmaxf(mrow[r], mx);
      const float corr = exp2f(mrow[r] - mnew);
      mrow[r] = mnew;
      const int rr = lg * 4 + r;
      float rs = 0.f;
#pragma unroll
      for (int ct = 0; ct < 8; ++ct) {
        const float p = exp2f(s[ct][r] - mnew);
        rs += p;
        Ps[w][rr][ct * 16 + lr] = f2bf(p);
      }
      rs = row16_sum(rs);
      lrow[r] = lrow[r] * corr + rs;
      o[0][r] *= corr; o[1][r] *= corr; o[2][r] *= corr; o[3][r] *= corr;
    }

    // Single barrier: LDS-only drain (prefetch vmem stays in flight).
    asm volatile("s_waitcnt lgkmcnt(0)" ::: "memory");
    __builtin_amdgcn_s_barrier();
    __builtin_amdgcn_sched_barrier(0);

    // PV: A = P (k-slot -> key kc*32+lg*8+e), B = V^T same key enumeration
    s8v pa[4];
#pragma unroll
    for (int kc = 0; kc < 4; ++kc)
      pa[kc] = *reinterpret_cast<const s8v*>(&Ps[w][lr][kc * 32 + lg * 8]);
#pragma unroll
    for (int dt = 0; dt < 4; ++dt) {
#pragma unroll
      for (int kc = 0; kc < 4; ++kc) {
        const s8v vbF = *reinterpret_cast<const s8v*>(&VT[dt * 16 + lr][kc * 32 + lg * 8]);
        o[dt] = __builtin_amdgcn_mfma_f32_16x16x32_bf16(pa[kc], vbF, o[dt], 0, 0, 0);
      }
    }
  };

  LOAD(kfA, vvA, 0);
  for (int t = 0; t < 16; t += 2) {
    LOAD(kfB, vvB, t + 1);          // prefetch odd tile over even ITER
    ITER(kfA, vvA, Vt0);
    if (t + 2 < 16) LOAD(kfA, vvA, t + 2);   // prefetch next even tile
    ITER(kfB, vvB, Vt1);
  }

  const int lbase = qt * 64 + w * 16 + lg * 4;
  unsigned short* obase = ab + (size_t)b * 2048 * 1024 + (size_t)h * 64;
#pragma unroll
  for (int r = 0; r < 4; ++r) {
    const float inv = 1.0f / lrow[r];
    unsigned short* orow = obase + (size_t)(lbase + r) * 1024;
    orow[0 + lr]  = f2bf(o[0][r] * inv);
    orow[16 + lr] = f2bf(o[1][r] * inv);
    orow[32 + lr] = f2bf(o[2][r] * inv);
    orow[48 + lr] = f2bf(o[3][r] * inv);
  }
}

// ---------------------------------------------------------------------------
// GEMM2 (MFMA): out = attn @ proj_w^T + bias, fp32 out.
// ---------------------------------------------------------------------------
__global__ __launch_bounds__(256)
void k_gemm_proj(const unsigned short* __restrict__ Ab,   // [4096][1024] bf16
                 const unsigned short* __restrict__ Bb,   // [1024][1024] bf16
                 const float* __restrict__ PB, float* __restrict__ OUT)
{
  __shared__ __align__(16) unsigned short Asm[128 * 32];
  __shared__ __align__(16) unsigned short Bsm[128 * 32];

  const int tid  = threadIdx.x;
  const int w    = tid >> 6;
  const int lane = tid & 63;
  const int lr   = lane & 15;
  const int lg   = lane >> 4;
  const int wm   = w >> 1, wn = w & 1;

  const int row0 = blockIdx.x << 7;
  const int col0 = blockIdx.y << 7;

  const int srow = (w << 5) + (lane >> 2);
  const int scol = (lane & 3) << 3;
  const unsigned short* Ag = Ab + (size_t)(row0 + srow) * 1024 + scol;
  const unsigned short* Bg = Bb + (size_t)(col0 + srow) * 1024 + scol;
  unsigned short* Al0 = &Asm[(w << 5) * 32];
  unsigned short* Al1 = Al0 + 512;
  unsigned short* Bl0 = &Bsm[(w << 5) * 32];
  unsigned short* Bl1 = Bl0 + 512;

  f4v acc[4][4];
#pragma unroll
  for (int m = 0; m < 4; ++m)
#pragma unroll
    for (int n = 0; n < 4; ++n) acc[m][n] = (f4v){0.f, 0.f, 0.f, 0.f};

  for (int k0 = 0; k0 < 1024; k0 += 32) {
    gl16(Ag + k0, Al0);
    gl16(Ag + k0 + 16 * 1024, Al1);
    gl16(Bg + k0, Bl0);
    gl16(Bg + k0 + 16 * 1024, Bl1);
    __syncthreads();

    s8v af[4], bfr[4];
#pragma unroll
    for (int m = 0; m < 4; ++m)
      af[m] = *reinterpret_cast<const s8v*>(&Asm[(wm * 64 + m * 16 + lr) * 32 + lg * 8]);
#pragma unroll
    for (int n = 0; n < 4; ++n)
      bfr[n] = *reinterpret_cast<const s8v*>(&Bsm[(wn * 64 + n * 16 + lr) * 32 + lg * 8]);
#pragma unroll
    for (int m = 0; m < 4; ++m)
#pragma unroll
      for (int n = 0; n < 4; ++n)
        acc[m][n] = __builtin_amdgcn_mfma_f32_16x16x32_bf16(af[m], bfr[n], acc[m][n], 0, 0, 0);
    __syncthreads();
  }

  float bias[4];
#pragma unroll
  for (int n = 0; n < 4; ++n) bias[n] = PB[col0 + wn * 64 + n * 16 + lr];

#pragma unroll
  for (int m = 0; m < 4; ++m) {
#pragma unroll
    for (int j = 0; j < 4; ++j) {
      const size_t token = row0 + wm * 64 + m * 16 + lg * 4 + j;
      float* orow = OUT + token * 1024 + col0 + wn * 64 + lr;
#pragma unroll
      for (int n = 0; n < 4; ++n) orow[n * 16] = acc[m][n][j] + bias[n];
    }
  }
}

// ---------------------------------------------------------------------------
extern "C" void kernel_launch(void* const* d_in, const int* in_sizes, int n_in,
                              void* d_out, int out_size, void* d_ws, size_t ws_size,
                              hipStream_t stream) {
  const float* X    = (const float*)d_in[0];
  const float* Wqkv = (const float*)d_in[1];
  const float* Wp   = (const float*)d_in[2];
  const float* Pb   = (const float*)d_in[3];
  const float* Ct   = (const float*)d_in[4];
  const float* St   = (const float*)d_in[5];
  float* OUT = (float*)d_out;

  // ws: Xb 8MB | Wb 6MB | Wpb 2MB | qb 8MB | kb 8MB | vt 8MB | ab 8MB = 48MB
  unsigned short* Xb  = (unsigned short*)d_ws;
  unsigned short* Wb  = Xb + (size_t)4194304;
  unsigned short* Wpb = Wb + (size_t)3145728;
  unsigned short* qb  = Wpb + (size_t)1048576;
  unsigned short* kb  = qb + (size_t)4194304;
  unsigned short* vt  = kb + (size_t)4194304;
  unsigned short* ab  = vt + (size_t)4194304;

  k_convert<<<dim3(4096), 256, 0, stream>>>(X, Wqkv, Wp, Xb, Wb, Wpb);
  k_gemm_qkv<<<dim3(32, 24), 256, 0, stream>>>(Xb, Wb, Ct, St, qb, kb, vt);
  k_attn<<<dim3(1024), 256, 0, stream>>>(qb, kb, vt, ab);
  k_gemm_proj<<<dim3(32, 8), 256, 0, stream>>>(ab, Wpb, Pb, OUT);
}

// Round 10
// 281.871 us; speedup vs baseline: 1.5564x; 1.5564x over previous
//
#include <hip/hip_runtime.h>

// B=2, L=2048, C=1024, H=16, D=64.
// [k_convert]   fp32 -> bf16: Xb (linear), Wb (q/k rows permuted so each head's
//               cols are [even-d | odd-d]), Wpb (linear).
// [k_gemm_qkv]  bf16 MFMA GEMM (M=4096,N=3072,K=1024), 128x128 tile, BK=32,
//               global_load_lds staging; epilogue: in-lane RoPE + q-scale for
//               q/k -> [b][h][l][64]; V stored TRANSPOSED vt[b][h][d][l].
// [k_attn]      flash attention, round-6 structure (KVBLK=128, LDS V^T via
//               straight contiguous copy, K direct from global, shfl softmax)
//               + XCD-aware block remap: blocks of the same (b,h) land on the
//               same XCD (4 heads/XCD -> 2MB K/V working set, L2-resident).
// [k_gemm_proj] bf16 MFMA GEMM (M=4096,N=1024,K=1024) + bias, fp32 out.

typedef __attribute__((ext_vector_type(8))) short s8v;            // 8 x bf16
typedef __attribute__((ext_vector_type(4))) float f4v;            // 4 x f32
typedef __attribute__((ext_vector_type(4))) unsigned short u16x4; // 4 x bf16

__device__ __forceinline__ unsigned short f2bf(float f) {
  unsigned int u = __float_as_uint(f);
  u += 0x7FFFu + ((u >> 16) & 1u);   // RNE
  return (unsigned short)(u >> 16);
}

__device__ __forceinline__ void gl16(const unsigned short* g, unsigned short* l) {
  __builtin_amdgcn_global_load_lds((const __attribute__((address_space(1))) void*)g,
                                   (__attribute__((address_space(3))) void*)l,
                                   16, 0, 0);
}

__device__ __forceinline__ s8v pack8(const float* p) {
  const float4 a = *reinterpret_cast<const float4*>(p);
  const float4 b = *reinterpret_cast<const float4*>(p + 4);
  s8v r;
  r[0]=(short)f2bf(a.x); r[1]=(short)f2bf(a.y); r[2]=(short)f2bf(a.z); r[3]=(short)f2bf(a.w);
  r[4]=(short)f2bf(b.x); r[5]=(short)f2bf(b.y); r[6]=(short)f2bf(b.z); r[7]=(short)f2bf(b.w);
  return r;
}

// ---------------------------------------------------------------------------
// Convert: blocks [0,2048) X (4M), [2048,3584) W (3M, q/k rows permuted),
//          [3584,4096) Wp (1M). 8 floats per thread.
// ---------------------------------------------------------------------------
__global__ __launch_bounds__(256)
void k_convert(const float* __restrict__ X, const float* __restrict__ W,
               const float* __restrict__ Wp,
               unsigned short* __restrict__ Xb, unsigned short* __restrict__ Wb,
               unsigned short* __restrict__ Wpb)
{
  const int bid = blockIdx.x, tid = threadIdx.x;
  if (bid < 2048) {
    const size_t e = (size_t)bid * 2048 + (size_t)tid * 8;
    *reinterpret_cast<s8v*>(Xb + e) = pack8(X + e);
  } else if (bid < 3584) {
    const size_t e = (size_t)(bid - 2048) * 2048 + (size_t)tid * 8;
    const int p = (int)(e >> 10);          // dst row
    const int col = (int)(e & 1023);
    int n;                                  // src row
    if (p < 2048) {                         // q/k: de-interleave head dims
      const int t = p >> 10;
      const int hh = (p & 1023) >> 6;
      const int c = p & 63;
      const int d = (c < 32) ? (c << 1) : (((c - 32) << 1) | 1);
      n = (t << 10) + (hh << 6) + d;
    } else {
      n = p;                                // v: identity
    }
    *reinterpret_cast<s8v*>(Wb + e) = pack8(W + (size_t)n * 1024 + col);
  } else {
    const size_t e = (size_t)(bid - 3584) * 2048 + (size_t)tid * 8;
    *reinterpret_cast<s8v*>(Wpb + e) = pack8(Wp + e);
  }
}

// ---------------------------------------------------------------------------
// GEMM1 (MFMA): qkv = Xb @ Wb^T, fused RoPE/scale epilogue.
// q/k -> bf16 [b][h][l][64] (permuted-d layout); v -> TRANSPOSED vt[b][h][d][l].
// ---------------------------------------------------------------------------
__global__ __launch_bounds__(256)
void k_gemm_qkv(const unsigned short* __restrict__ Ab,   // [4096][1024]
                const unsigned short* __restrict__ Bb,   // [3072][1024] permuted
                const float* __restrict__ Ct, const float* __restrict__ St,
                unsigned short* __restrict__ qb, unsigned short* __restrict__ kb,
                unsigned short* __restrict__ vt)
{
  __shared__ __align__(16) unsigned short Asm[128 * 32];
  __shared__ __align__(16) unsigned short Bsm[128 * 32];

  const int tid  = threadIdx.x;
  const int w    = tid >> 6;
  const int lane = tid & 63;
  const int lr   = lane & 15;
  const int lg   = lane >> 4;
  const int wm   = w >> 1, wn = w & 1;

  const int row0 = blockIdx.x << 7;
  const int col0 = blockIdx.y << 7;

  const int srow = (w << 5) + (lane >> 2);
  const int scol = (lane & 3) << 3;
  const unsigned short* Ag = Ab + (size_t)(row0 + srow) * 1024 + scol;
  const unsigned short* Bg = Bb + (size_t)(col0 + srow) * 1024 + scol;
  unsigned short* Al0 = &Asm[(w << 5) * 32];
  unsigned short* Al1 = Al0 + 512;
  unsigned short* Bl0 = &Bsm[(w << 5) * 32];
  unsigned short* Bl1 = Bl0 + 512;

  f4v acc[4][4];
#pragma unroll
  for (int m = 0; m < 4; ++m)
#pragma unroll
    for (int n = 0; n < 4; ++n) acc[m][n] = (f4v){0.f, 0.f, 0.f, 0.f};

  for (int k0 = 0; k0 < 1024; k0 += 32) {
    gl16(Ag + k0, Al0);
    gl16(Ag + k0 + 16 * 1024, Al1);
    gl16(Bg + k0, Bl0);
    gl16(Bg + k0 + 16 * 1024, Bl1);
    __syncthreads();

    s8v af[4], bfr[4];
#pragma unroll
    for (int m = 0; m < 4; ++m)
      af[m] = *reinterpret_cast<const s8v*>(&Asm[(wm * 64 + m * 16 + lr) * 32 + lg * 8]);
#pragma unroll
    for (int n = 0; n < 4; ++n)
      bfr[n] = *reinterpret_cast<const s8v*>(&Bsm[(wn * 64 + n * 16 + lr) * 32 + lg * 8]);
#pragma unroll
    for (int m = 0; m < 4; ++m)
#pragma unroll
      for (int n = 0; n < 4; ++n)
        acc[m][n] = __builtin_amdgcn_mfma_f32_16x16x32_bf16(af[m], bfr[n], acc[m][n], 0, 0, 0);
    __syncthreads();
  }

  const int colbase = col0 + wn * 64;
  const int t  = colbase >> 10;
  const int h  = (colbase & 1023) >> 6;

  if (t == 2) {
    // V: transposed store vt[b][h][d][l], 4 consecutive tokens packed per 8B.
#pragma unroll
    for (int m = 0; m < 4; ++m) {
      const int token = row0 + wm * 64 + m * 16 + lg * 4;
      const int bI = token >> 11;
      const int lI = token & 2047;
      unsigned short* vbase = vt + (((size_t)bI * 16 + h) * 64) * 2048 + lI;
#pragma unroll
      for (int n = 0; n < 4; ++n) {
        const int d = n * 16 + lr;
        u16x4 pk;
        pk[0] = f2bf(acc[m][n][0]); pk[1] = f2bf(acc[m][n][1]);
        pk[2] = f2bf(acc[m][n][2]); pk[3] = f2bf(acc[m][n][3]);
        *reinterpret_cast<u16x4*>(vbase + (size_t)d * 2048) = pk;
      }
    }
  } else {
    unsigned short* dst = (t == 0) ? qb : kb;
    const float sc = (t == 0) ? 0.125f : 1.0f;   // logits scale folded into q
#pragma unroll
    for (int m = 0; m < 4; ++m) {
#pragma unroll
      for (int j = 0; j < 4; ++j) {
        const int token = row0 + wm * 64 + m * 16 + lg * 4 + j;
        const int bI = token >> 11;
        const int lI = token & 2047;
        unsigned short* rowp = dst + (((size_t)bI * 16 + h) * 2048 + lI) * 64;
#pragma unroll
        for (int pn = 0; pn < 2; ++pn) {
          const int d2 = pn * 16 + lr;
          const float c = Ct[lI * 32 + d2];
          const float s = St[lI * 32 + d2];
          const float e = acc[m][pn][j];
          const float o = acc[m][pn + 2][j];
          rowp[d2]      = f2bf((e * c - o * s) * sc);
          rowp[32 + d2] = f2bf((e * s + o * c) * sc);
        }
      }
    }
  }
}

// ---------------------------------------------------------------------------
// Flash attention: 4 waves, wave w owns 16 q-rows; KVBLK=128. K frags direct
// from global (now L2-resident via XCD grouping). V^T staged to LDS by
// straight contiguous copy (conflict-free b128). Shfl softmax (round-6 base).
// XCD remap: hw XCD = blockIdx%8 -> give each XCD 4 whole heads so the 32
// q-blocks sharing a head's 512KB K/V hit the same 4MB L2.
// ---------------------------------------------------------------------------
__global__ __launch_bounds__(256)
void k_attn(const unsigned short* __restrict__ qb,
            const unsigned short* __restrict__ kb,
            const unsigned short* __restrict__ vt,
            unsigned short* __restrict__ ab)
{
  __shared__ unsigned short Ps[4][16][132];   // per-wave P tile (16 q x 128 k)
  __shared__ unsigned short Vt[64][132];      // V^T tile: [d][key 0..127]

  const int tid  = threadIdx.x;
  const int w    = tid >> 6;
  const int lane = tid & 63;
  const int lr   = lane & 15;
  const int lg   = lane >> 4;

  // XCD-aware remap (bijective): g = hw XCD, 4 heads per XCD, qt contiguous.
  const int i  = blockIdx.x;
  const int g  = i & 7;
  const int j  = i >> 3;              // 0..127
  const int bh = g * 4 + (j >> 5);    // 0..31 (b*16+h)
  const int qt = j & 31;
  const int h  = bh & 15;
  const int b  = bh >> 4;

  const size_t bhs = ((size_t)b * 16 + h) * 2048;
  const unsigned short* Qp  = qb + (bhs + (size_t)qt * 64 + w * 16) * 64;
  const unsigned short* Kp  = kb + bhs * 64;
  const unsigned short* Vg  = vt + bhs * 64;   // [d][l] for this (b,h)

  const s8v qa0 = *reinterpret_cast<const s8v*>(Qp + lr * 64 + 0 + lg * 8);
  const s8v qa1 = *reinterpret_cast<const s8v*>(Qp + lr * 64 + 32 + lg * 8);

  f4v o[4];
#pragma unroll
  for (int i2 = 0; i2 < 4; ++i2) o[i2] = (f4v){0.f, 0.f, 0.f, 0.f};
  float mrow[4] = {-1e30f, -1e30f, -1e30f, -1e30f};
  float lrow[4] = {0.f, 0.f, 0.f, 0.f};

  // V staging: thread covers 64B of row sd: shorts [sk + j*32, +8) j=0..3
  const int sd = tid >> 2;             // d row 0..63
  const int sk = (tid & 3) << 3;       // 0,8,16,24 shorts

  for (int kt = 0; kt < 16; ++kt) {
    const unsigned short* Kt = Kp + (size_t)kt * 128 * 64;

    // issue V loads early (in flight across barrier / QK / softmax)
    const unsigned short* vsrc = Vg + (size_t)sd * 2048 + kt * 128 + sk;
    s8v vv[4];
#pragma unroll
    for (int jj = 0; jj < 4; ++jj)
      vv[jj] = *reinterpret_cast<const s8v*>(vsrc + jj * 32);

    __syncthreads();   // previous iteration's PV readers done with Vt
#pragma unroll
    for (int jj = 0; jj < 4; ++jj)
      *reinterpret_cast<s8v*>(&Vt[sd][sk + jj * 32]) = vv[jj];

    // S = q . K^T over 128 keys (8 column-tiles of 16)
    f4v s[8];
#pragma unroll
    for (int ct = 0; ct < 8; ++ct) {
      const s8v kf0 = *reinterpret_cast<const s8v*>(Kt + (ct * 16 + lr) * 64 + 0 + lg * 8);
      const s8v kf1 = *reinterpret_cast<const s8v*>(Kt + (ct * 16 + lr) * 64 + 32 + lg * 8);
      f4v z = (f4v){0.f, 0.f, 0.f, 0.f};
      z = __builtin_amdgcn_mfma_f32_16x16x32_bf16(qa0, kf0, z, 0, 0, 0);
      z = __builtin_amdgcn_mfma_f32_16x16x32_bf16(qa1, kf1, z, 0, 0, 0);
      s[ct] = z;
    }

    // online softmax over 128 keys at once
#pragma unroll
    for (int r = 0; r < 4; ++r) {
      float mx = fmaxf(fmaxf(fmaxf(s[0][r], s[1][r]), fmaxf(s[2][r], s[3][r])),
                       fmaxf(fmaxf(s[4][r], s[5][r]), fmaxf(s[6][r], s[7][r])));
#pragma unroll
      for (int mk = 1; mk <= 8; mk <<= 1) mx = fmaxf(mx, __shfl_xor(mx, mk));
      const float mnew = fmaxf(mrow[r], mx);
      const float corr = __expf(mrow[r] - mnew);
      mrow[r] = mnew;
      const int rr = lg * 4 + r;
      float rs = 0.f;
#pragma unroll
      for (int ct = 0; ct < 8; ++ct) {
        const float p = __expf(s[ct][r] - mnew);
        rs += p;
        Ps[w][rr][ct * 16 + lr] = f2bf(p);
      }
#pragma unroll
      for (int mk = 1; mk <= 8; mk <<= 1) rs += __shfl_xor(rs, mk);
      lrow[r] = lrow[r] * corr + rs;
      o[0][r] *= corr; o[1][r] *= corr; o[2][r] *= corr; o[3][r] *= corr;
    }
    __syncthreads();   // Vt fully staged (Ps is wave-private)

    // PV: A = P (k-slot -> key kc*32+lg*8+e), B = V^T same key enumeration
    s8v pa[4];
#pragma unroll
    for (int kc = 0; kc < 4; ++kc)
      pa[kc] = *reinterpret_cast<const s8v*>(&Ps[w][lr][kc * 32 + lg * 8]);
#pragma unroll
    for (int dt = 0; dt < 4; ++dt) {
#pragma unroll
      for (int kc = 0; kc < 4; ++kc) {
        const s8v vbF = *reinterpret_cast<const s8v*>(&Vt[dt * 16 + lr][kc * 32 + lg * 8]);
        o[dt] = __builtin_amdgcn_mfma_f32_16x16x32_bf16(pa[kc], vbF, o[dt], 0, 0, 0);
      }
    }
  }

  const int lbase = qt * 64 + w * 16 + lg * 4;
  unsigned short* obase = ab + (size_t)b * 2048 * 1024 + (size_t)h * 64;
#pragma unroll
  for (int r = 0; r < 4; ++r) {
    const float inv = 1.0f / lrow[r];
    unsigned short* orow = obase + (size_t)(lbase + r) * 1024;
    orow[0 + lr]  = f2bf(o[0][r] * inv);
    orow[16 + lr] = f2bf(o[1][r] * inv);
    orow[32 + lr] = f2bf(o[2][r] * inv);
    orow[48 + lr] = f2bf(o[3][r] * inv);
  }
}

// ---------------------------------------------------------------------------
// GEMM2 (MFMA): out = attn @ proj_w^T + bias, fp32 out.
// ---------------------------------------------------------------------------
__global__ __launch_bounds__(256)
void k_gemm_proj(const unsigned short* __restrict__ Ab,   // [4096][1024] bf16
                 const unsigned short* __restrict__ Bb,   // [1024][1024] bf16
                 const float* __restrict__ PB, float* __restrict__ OUT)
{
  __shared__ __align__(16) unsigned short Asm[128 * 32];
  __shared__ __align__(16) unsigned short Bsm[128 * 32];

  const int tid  = threadIdx.x;
  const int w    = tid >> 6;
  const int lane = tid & 63;
  const int lr   = lane & 15;
  const int lg   = lane >> 4;
  const int wm   = w >> 1, wn = w & 1;

  const int row0 = blockIdx.x << 7;
  const int col0 = blockIdx.y << 7;

  const int srow = (w << 5) + (lane >> 2);
  const int scol = (lane & 3) << 3;
  const unsigned short* Ag = Ab + (size_t)(row0 + srow) * 1024 + scol;
  const unsigned short* Bg = Bb + (size_t)(col0 + srow) * 1024 + scol;
  unsigned short* Al0 = &Asm[(w << 5) * 32];
  unsigned short* Al1 = Al0 + 512;
  unsigned short* Bl0 = &Bsm[(w << 5) * 32];
  unsigned short* Bl1 = Bl0 + 512;

  f4v acc[4][4];
#pragma unroll
  for (int m = 0; m < 4; ++m)
#pragma unroll
    for (int n = 0; n < 4; ++n) acc[m][n] = (f4v){0.f, 0.f, 0.f, 0.f};

  for (int k0 = 0; k0 < 1024; k0 += 32) {
    gl16(Ag + k0, Al0);
    gl16(Ag + k0 + 16 * 1024, Al1);
    gl16(Bg + k0, Bl0);
    gl16(Bg + k0 + 16 * 1024, Bl1);
    __syncthreads();

    s8v af[4], bfr[4];
#pragma unroll
    for (int m = 0; m < 4; ++m)
      af[m] = *reinterpret_cast<const s8v*>(&Asm[(wm * 64 + m * 16 + lr) * 32 + lg * 8]);
#pragma unroll
    for (int n = 0; n < 4; ++n)
      bfr[n] = *reinterpret_cast<const s8v*>(&Bsm[(wn * 64 + n * 16 + lr) * 32 + lg * 8]);
#pragma unroll
    for (int m = 0; m < 4; ++m)
#pragma unroll
      for (int n = 0; n < 4; ++n)
        acc[m][n] = __builtin_amdgcn_mfma_f32_16x16x32_bf16(af[m], bfr[n], acc[m][n], 0, 0, 0);
    __syncthreads();
  }

  float bias[4];
#pragma unroll
  for (int n = 0; n < 4; ++n) bias[n] = PB[col0 + wn * 64 + n * 16 + lr];

#pragma unroll
  for (int m = 0; m < 4; ++m) {
#pragma unroll
    for (int j = 0; j < 4; ++j) {
      const size_t token = row0 + wm * 64 + m * 16 + lg * 4 + j;
      float* orow = OUT + token * 1024 + col0 + wn * 64 + lr;
#pragma unroll
      for (int n = 0; n < 4; ++n) orow[n * 16] = acc[m][n][j] + bias[n];
    }
  }
}

// ---------------------------------------------------------------------------
extern "C" void kernel_launch(void* const* d_in, const int* in_sizes, int n_in,
                              void* d_out, int out_size, void* d_ws, size_t ws_size,
                              hipStream_t stream) {
  const float* X    = (const float*)d_in[0];
  const float* Wqkv = (const float*)d_in[1];
  const float* Wp   = (const float*)d_in[2];
  const float* Pb   = (const float*)d_in[3];
  const float* Ct   = (const float*)d_in[4];
  const float* St   = (const float*)d_in[5];
  float* OUT = (float*)d_out;

  // ws: Xb 8MB | Wb 6MB | Wpb 2MB | qb 8MB | kb 8MB | vt 8MB | ab 8MB = 48MB
  unsigned short* Xb  = (unsigned short*)d_ws;
  unsigned short* Wb  = Xb + (size_t)4194304;
  unsigned short* Wpb = Wb + (size_t)3145728;
  unsigned short* qb  = Wpb + (size_t)1048576;
  unsigned short* kb  = qb + (size_t)4194304;
  unsigned short* vt  = kb + (size_t)4194304;
  unsigned short* ab  = vt + (size_t)4194304;

  k_convert<<<dim3(4096), 256, 0, stream>>>(X, Wqkv, Wp, Xb, Wb, Wpb);
  k_gemm_qkv<<<dim3(32, 24), 256, 0, stream>>>(Xb, Wb, Ct, St, qb, kb, vt);
  k_attn<<<dim3(1024), 256, 0, stream>>>(qb, kb, vt, ab);
  k_gemm_proj<<<dim3(32, 8), 256, 0, stream>>>(ab, Wpb, Pb, OUT);
}

// Round 11
// 248.995 us; speedup vs baseline: 1.7619x; 1.1320x over previous
//
#include <hip/hip_runtime.h>

// B=2, L=2048, C=1024, H=16, D=64.
// [k_convert]   fp32 -> bf16: Xb (linear), Wb (q/k rows permuted so each head's
//               cols are [even-d | odd-d]), Wpb (linear).
// [k_gemm_qkv]  bf16 MFMA GEMM (M=4096,N=3072,K=1024), 128x128 tile, BK=32,
//               global_load_lds staging; epilogue: in-lane RoPE + q-scale for
//               q/k -> [b][h][l][64]; V stored TRANSPOSED vt[b][h][d][l].
// [k_attn]      flash attention, KVBLK=128, XCD remap. NEW: K tile staged into
//               LDS via global_load_lds (shared by all 4 waves, 4x dedup) with
//               XOR-swizzled SOURCE addressing (linear LDS dest, swizzled read
//               -> bank-optimal both sides); V reg-staged with loads issued
//               after barrier 2 (hidden under full compute phase).
// [k_gemm_proj] bf16 MFMA GEMM (M=4096,N=1024,K=1024) + bias, fp32 out.

typedef __attribute__((ext_vector_type(8))) short s8v;            // 8 x bf16
typedef __attribute__((ext_vector_type(4))) float f4v;            // 4 x f32
typedef __attribute__((ext_vector_type(4))) unsigned short u16x4; // 4 x bf16

__device__ __forceinline__ unsigned short f2bf(float f) {
  unsigned int u = __float_as_uint(f);
  u += 0x7FFFu + ((u >> 16) & 1u);   // RNE
  return (unsigned short)(u >> 16);
}

__device__ __forceinline__ void gl16(const unsigned short* g, unsigned short* l) {
  __builtin_amdgcn_global_load_lds((const __attribute__((address_space(1))) void*)g,
                                   (__attribute__((address_space(3))) void*)l,
                                   16, 0, 0);
}

__device__ __forceinline__ s8v pack8(const float* p) {
  const float4 a = *reinterpret_cast<const float4*>(p);
  const float4 b = *reinterpret_cast<const float4*>(p + 4);
  s8v r;
  r[0]=(short)f2bf(a.x); r[1]=(short)f2bf(a.y); r[2]=(short)f2bf(a.z); r[3]=(short)f2bf(a.w);
  r[4]=(short)f2bf(b.x); r[5]=(short)f2bf(b.y); r[6]=(short)f2bf(b.z); r[7]=(short)f2bf(b.w);
  return r;
}

// ---------------------------------------------------------------------------
// Convert: blocks [0,2048) X (4M), [2048,3584) W (3M, q/k rows permuted),
//          [3584,4096) Wp (1M). 8 floats per thread.
// ---------------------------------------------------------------------------
__global__ __launch_bounds__(256)
void k_convert(const float* __restrict__ X, const float* __restrict__ W,
               const float* __restrict__ Wp,
               unsigned short* __restrict__ Xb, unsigned short* __restrict__ Wb,
               unsigned short* __restrict__ Wpb)
{
  const int bid = blockIdx.x, tid = threadIdx.x;
  if (bid < 2048) {
    const size_t e = (size_t)bid * 2048 + (size_t)tid * 8;
    *reinterpret_cast<s8v*>(Xb + e) = pack8(X + e);
  } else if (bid < 3584) {
    const size_t e = (size_t)(bid - 2048) * 2048 + (size_t)tid * 8;
    const int p = (int)(e >> 10);          // dst row
    const int col = (int)(e & 1023);
    int n;                                  // src row
    if (p < 2048) {                         // q/k: de-interleave head dims
      const int t = p >> 10;
      const int hh = (p & 1023) >> 6;
      const int c = p & 63;
      const int d = (c < 32) ? (c << 1) : (((c - 32) << 1) | 1);
      n = (t << 10) + (hh << 6) + d;
    } else {
      n = p;                                // v: identity
    }
    *reinterpret_cast<s8v*>(Wb + e) = pack8(W + (size_t)n * 1024 + col);
  } else {
    const size_t e = (size_t)(bid - 3584) * 2048 + (size_t)tid * 8;
    *reinterpret_cast<s8v*>(Wpb + e) = pack8(Wp + e);
  }
}

// ---------------------------------------------------------------------------
// GEMM1 (MFMA): qkv = Xb @ Wb^T, fused RoPE/scale epilogue.
// q/k -> bf16 [b][h][l][64] (permuted-d layout); v -> TRANSPOSED vt[b][h][d][l].
// ---------------------------------------------------------------------------
__global__ __launch_bounds__(256)
void k_gemm_qkv(const unsigned short* __restrict__ Ab,   // [4096][1024]
                const unsigned short* __restrict__ Bb,   // [3072][1024] permuted
                const float* __restrict__ Ct, const float* __restrict__ St,
                unsigned short* __restrict__ qb, unsigned short* __restrict__ kb,
                unsigned short* __restrict__ vt)
{
  __shared__ __align__(16) unsigned short Asm[128 * 32];
  __shared__ __align__(16) unsigned short Bsm[128 * 32];

  const int tid  = threadIdx.x;
  const int w    = tid >> 6;
  const int lane = tid & 63;
  const int lr   = lane & 15;
  const int lg   = lane >> 4;
  const int wm   = w >> 1, wn = w & 1;

  const int row0 = blockIdx.x << 7;
  const int col0 = blockIdx.y << 7;

  const int srow = (w << 5) + (lane >> 2);
  const int scol = (lane & 3) << 3;
  const unsigned short* Ag = Ab + (size_t)(row0 + srow) * 1024 + scol;
  const unsigned short* Bg = Bb + (size_t)(col0 + srow) * 1024 + scol;
  unsigned short* Al0 = &Asm[(w << 5) * 32];
  unsigned short* Al1 = Al0 + 512;
  unsigned short* Bl0 = &Bsm[(w << 5) * 32];
  unsigned short* Bl1 = Bl0 + 512;

  f4v acc[4][4];
#pragma unroll
  for (int m = 0; m < 4; ++m)
#pragma unroll
    for (int n = 0; n < 4; ++n) acc[m][n] = (f4v){0.f, 0.f, 0.f, 0.f};

  for (int k0 = 0; k0 < 1024; k0 += 32) {
    gl16(Ag + k0, Al0);
    gl16(Ag + k0 + 16 * 1024, Al1);
    gl16(Bg + k0, Bl0);
    gl16(Bg + k0 + 16 * 1024, Bl1);
    __syncthreads();

    s8v af[4], bfr[4];
#pragma unroll
    for (int m = 0; m < 4; ++m)
      af[m] = *reinterpret_cast<const s8v*>(&Asm[(wm * 64 + m * 16 + lr) * 32 + lg * 8]);
#pragma unroll
    for (int n = 0; n < 4; ++n)
      bfr[n] = *reinterpret_cast<const s8v*>(&Bsm[(wn * 64 + n * 16 + lr) * 32 + lg * 8]);
#pragma unroll
    for (int m = 0; m < 4; ++m)
#pragma unroll
      for (int n = 0; n < 4; ++n)
        acc[m][n] = __builtin_amdgcn_mfma_f32_16x16x32_bf16(af[m], bfr[n], acc[m][n], 0, 0, 0);
    __syncthreads();
  }

  const int colbase = col0 + wn * 64;
  const int t  = colbase >> 10;
  const int h  = (colbase & 1023) >> 6;

  if (t == 2) {
    // V: transposed store vt[b][h][d][l], 4 consecutive tokens packed per 8B.
#pragma unroll
    for (int m = 0; m < 4; ++m) {
      const int token = row0 + wm * 64 + m * 16 + lg * 4;
      const int bI = token >> 11;
      const int lI = token & 2047;
      unsigned short* vbase = vt + (((size_t)bI * 16 + h) * 64) * 2048 + lI;
#pragma unroll
      for (int n = 0; n < 4; ++n) {
        const int d = n * 16 + lr;
        u16x4 pk;
        pk[0] = f2bf(acc[m][n][0]); pk[1] = f2bf(acc[m][n][1]);
        pk[2] = f2bf(acc[m][n][2]); pk[3] = f2bf(acc[m][n][3]);
        *reinterpret_cast<u16x4*>(vbase + (size_t)d * 2048) = pk;
      }
    }
  } else {
    unsigned short* dst = (t == 0) ? qb : kb;
    const float sc = (t == 0) ? 0.125f : 1.0f;   // logits scale folded into q
#pragma unroll
    for (int m = 0; m < 4; ++m) {
#pragma unroll
      for (int j = 0; j < 4; ++j) {
        const int token = row0 + wm * 64 + m * 16 + lg * 4 + j;
        const int bI = token >> 11;
        const int lI = token & 2047;
        unsigned short* rowp = dst + (((size_t)bI * 16 + h) * 2048 + lI) * 64;
#pragma unroll
        for (int pn = 0; pn < 2; ++pn) {
          const int d2 = pn * 16 + lr;
          const float c = Ct[lI * 32 + d2];
          const float s = St[lI * 32 + d2];
          const float e = acc[m][pn][j];
          const float o = acc[m][pn + 2][j];
          rowp[d2]      = f2bf((e * c - o * s) * sc);
          rowp[32 + d2] = f2bf((e * s + o * c) * sc);
        }
      }
    }
  }
}

// ---------------------------------------------------------------------------
// Flash attention: 4 waves, wave w owns 16 q-rows; KVBLK=128; XCD remap.
// K tile in LDS via global_load_lds (shared across waves): linear LDS dest,
// XOR-swizzled global source slot s_src=(lane&7)^(lane>>3); QK reads with
// slot (4h+lg)^(lr&7) -> swizzle cancels, banks optimal (8 lanes/16B slot).
// V reg-staged; loads issued after barrier 2 (hidden under QK+softmax+PV).
// ---------------------------------------------------------------------------
__global__ __launch_bounds__(256)
void k_attn(const unsigned short* __restrict__ qb,
            const unsigned short* __restrict__ kb,
            const unsigned short* __restrict__ vt,
            unsigned short* __restrict__ ab)
{
  __shared__ unsigned short Ps[4][16][132];        // per-wave P tile
  __shared__ unsigned short Vt[64][132];           // V^T tile [d][key]
  __shared__ __align__(16) unsigned short Kt[128 * 64];  // K tile, swizzled

  const int tid  = threadIdx.x;
  const int w    = tid >> 6;
  const int lane = tid & 63;
  const int lr   = lane & 15;
  const int lg   = lane >> 4;

  // XCD-aware remap (bijective): g = hw XCD, 4 heads per XCD, qt contiguous.
  const int i  = blockIdx.x;
  const int g  = i & 7;
  const int j  = i >> 3;              // 0..127
  const int bh = g * 4 + (j >> 5);    // 0..31 (b*16+h)
  const int qt = j & 31;
  const int h  = bh & 15;
  const int b  = bh >> 4;

  const size_t bhs = ((size_t)b * 16 + h) * 2048;
  const unsigned short* Qp  = qb + (bhs + (size_t)qt * 64 + w * 16) * 64;
  const unsigned short* Kp  = kb + bhs * 64;
  const unsigned short* Vg  = vt + bhs * 64;   // [d][l] for this (b,h)

  const s8v qa0 = *reinterpret_cast<const s8v*>(Qp + lr * 64 + 0 + lg * 8);
  const s8v qa1 = *reinterpret_cast<const s8v*>(Qp + lr * 64 + 32 + lg * 8);

  f4v o[4];
#pragma unroll
  for (int i2 = 0; i2 < 4; ++i2) o[i2] = (f4v){0.f, 0.f, 0.f, 0.f};
  float mrow[4] = {-1e30f, -1e30f, -1e30f, -1e30f};
  float lrow[4] = {0.f, 0.f, 0.f, 0.f};

  // V staging: thread covers 64B of row sd: shorts [sk + j*32, +8) j=0..3
  const int sd = tid >> 2;             // d row 0..63
  const int sk = (tid & 3) << 3;       // 0,8,16,24 shorts

  // K staging geometry: per round c, wave w covers rows [(c*4+w)*8, +8).
  // Lane covers row +ksrow, source slot kslot (inverse-swizzle of its linear
  // LDS landing slot lane&7):  kslot = (lane&7) ^ ksrow.
  const int ksrow = lane >> 3;               // 0..7
  const int kslot = (lane & 7) ^ ksrow;      // swizzled 16B slot in source row

  // prologue: V regs for tile 0
  s8v vv[4];
  {
    const unsigned short* vsrc = Vg + (size_t)sd * 2048 + 0 * 128 + sk;
#pragma unroll
    for (int jj = 0; jj < 4; ++jj)
      vv[jj] = *reinterpret_cast<const s8v*>(vsrc + jj * 32);
  }

  for (int kt = 0; kt < 16; ++kt) {
    const unsigned short* Ktg = Kp + (size_t)kt * 128 * 64;

    __syncthreads();   // all waves done reading Kt (QK) / Vt (PV) of prev tile

    // stage V from regs (straight contiguous b128 writes, conflict-free)
#pragma unroll
    for (int jj = 0; jj < 4; ++jj)
      *reinterpret_cast<s8v*>(&Vt[sd][sk + jj * 32]) = vv[jj];

    // stage K via global_load_lds: linear LDS dest, swizzled source
#pragma unroll
    for (int c = 0; c < 4; ++c) {
      const int rbase = (c * 4 + w) * 8;
      gl16(Ktg + (size_t)(rbase + ksrow) * 64 + kslot * 8,
           &Kt[(size_t)rbase * 64]);
    }

    __syncthreads();   // drains vmcnt+lgkmcnt: Kt and Vt staged & visible

    // issue next tile's V loads now -> hidden under QK+softmax+PV+barrier
    if (kt < 15) {
      const unsigned short* vsrc = Vg + (size_t)sd * 2048 + (kt + 1) * 128 + sk;
#pragma unroll
      for (int jj = 0; jj < 4; ++jj)
        vv[jj] = *reinterpret_cast<const s8v*>(vsrc + jj * 32);
    }

    // S = q . K^T over 128 keys (8 column-tiles of 16), K from LDS
    f4v s[8];
#pragma unroll
    for (int ct = 0; ct < 8; ++ct) {
      const int row = ct * 16 + lr;
      const int sw  = (lr & 7) << 3;
      const s8v kf0 = *reinterpret_cast<const s8v*>(&Kt[row * 64 + ((lg * 8) ^ sw)]);
      const s8v kf1 = *reinterpret_cast<const s8v*>(&Kt[row * 64 + ((32 + lg * 8) ^ sw)]);
      f4v z = (f4v){0.f, 0.f, 0.f, 0.f};
      z = __builtin_amdgcn_mfma_f32_16x16x32_bf16(qa0, kf0, z, 0, 0, 0);
      z = __builtin_amdgcn_mfma_f32_16x16x32_bf16(qa1, kf1, z, 0, 0, 0);
      s[ct] = z;
    }

    // online softmax over 128 keys at once
#pragma unroll
    for (int r = 0; r < 4; ++r) {
      float mx = fmaxf(fmaxf(fmaxf(s[0][r], s[1][r]), fmaxf(s[2][r], s[3][r])),
                       fmaxf(fmaxf(s[4][r], s[5][r]), fmaxf(s[6][r], s[7][r])));
#pragma unroll
      for (int mk = 1; mk <= 8; mk <<= 1) mx = fmaxf(mx, __shfl_xor(mx, mk));
      const float mnew = fmaxf(mrow[r], mx);
      const float corr = __expf(mrow[r] - mnew);
      mrow[r] = mnew;
      const int rr = lg * 4 + r;
      float rs = 0.f;
#pragma unroll
      for (int ct = 0; ct < 8; ++ct) {
        const float p = __expf(s[ct][r] - mnew);
        rs += p;
        Ps[w][rr][ct * 16 + lr] = f2bf(p);
      }
#pragma unroll
      for (int mk = 1; mk <= 8; mk <<= 1) rs += __shfl_xor(rs, mk);
      lrow[r] = lrow[r] * corr + rs;
      o[0][r] *= corr; o[1][r] *= corr; o[2][r] *= corr; o[3][r] *= corr;
    }

    // PV: A = P (k-slot -> key kc*32+lg*8+e), B = V^T same key enumeration
    s8v pa[4];
#pragma unroll
    for (int kc = 0; kc < 4; ++kc)
      pa[kc] = *reinterpret_cast<const s8v*>(&Ps[w][lr][kc * 32 + lg * 8]);
#pragma unroll
    for (int dt = 0; dt < 4; ++dt) {
#pragma unroll
      for (int kc = 0; kc < 4; ++kc) {
        const s8v vbF = *reinterpret_cast<const s8v*>(&Vt[dt * 16 + lr][kc * 32 + lg * 8]);
        o[dt] = __builtin_amdgcn_mfma_f32_16x16x32_bf16(pa[kc], vbF, o[dt], 0, 0, 0);
      }
    }
  }

  const int lbase = qt * 64 + w * 16 + lg * 4;
  unsigned short* obase = ab + (size_t)b * 2048 * 1024 + (size_t)h * 64;
#pragma unroll
  for (int r = 0; r < 4; ++r) {
    const float inv = 1.0f / lrow[r];
    unsigned short* orow = obase + (size_t)(lbase + r) * 1024;
    orow[0 + lr]  = f2bf(o[0][r] * inv);
    orow[16 + lr] = f2bf(o[1][r] * inv);
    orow[32 + lr] = f2bf(o[2][r] * inv);
    orow[48 + lr] = f2bf(o[3][r] * inv);
  }
}

// ---------------------------------------------------------------------------
// GEMM2 (MFMA): out = attn @ proj_w^T + bias, fp32 out.
// ---------------------------------------------------------------------------
__global__ __launch_bounds__(256)
void k_gemm_proj(const unsigned short* __restrict__ Ab,   // [4096][1024] bf16
                 const unsigned short* __restrict__ Bb,   // [1024][1024] bf16
                 const float* __restrict__ PB, float* __restrict__ OUT)
{
  __shared__ __align__(16) unsigned short Asm[128 * 32];
  __shared__ __align__(16) unsigned short Bsm[128 * 32];

  const int tid  = threadIdx.x;
  const int w    = tid >> 6;
  const int lane = tid & 63;
  const int lr   = lane & 15;
  const int lg   = lane >> 4;
  const int wm   = w >> 1, wn = w & 1;

  const int row0 = blockIdx.x << 7;
  const int col0 = blockIdx.y << 7;

  const int srow = (w << 5) + (lane >> 2);
  const int scol = (lane & 3) << 3;
  const unsigned short* Ag = Ab + (size_t)(row0 + srow) * 1024 + scol;
  const unsigned short* Bg = Bb + (size_t)(col0 + srow) * 1024 + scol;
  unsigned short* Al0 = &Asm[(w << 5) * 32];
  unsigned short* Al1 = Al0 + 512;
  unsigned short* Bl0 = &Bsm[(w << 5) * 32];
  unsigned short* Bl1 = Bl0 + 512;

  f4v acc[4][4];
#pragma unroll
  for (int m = 0; m < 4; ++m)
#pragma unroll
    for (int n = 0; n < 4; ++n) acc[m][n] = (f4v){0.f, 0.f, 0.f, 0.f};

  for (int k0 = 0; k0 < 1024; k0 += 32) {
    gl16(Ag + k0, Al0);
    gl16(Ag + k0 + 16 * 1024, Al1);
    gl16(Bg + k0, Bl0);
    gl16(Bg + k0 + 16 * 1024, Bl1);
    __syncthreads();

    s8v af[4], bfr[4];
#pragma unroll
    for (int m = 0; m < 4; ++m)
      af[m] = *reinterpret_cast<const s8v*>(&Asm[(wm * 64 + m * 16 + lr) * 32 + lg * 8]);
#pragma unroll
    for (int n = 0; n < 4; ++n)
      bfr[n] = *reinterpret_cast<const s8v*>(&Bsm[(wn * 64 + n * 16 + lr) * 32 + lg * 8]);
#pragma unroll
    for (int m = 0; m < 4; ++m)
#pragma unroll
      for (int n = 0; n < 4; ++n)
        acc[m][n] = __builtin_amdgcn_mfma_f32_16x16x32_bf16(af[m], bfr[n], acc[m][n], 0, 0, 0);
    __syncthreads();
  }

  float bias[4];
#pragma unroll
  for (int n = 0; n < 4; ++n) bias[n] = PB[col0 + wn * 64 + n * 16 + lr];

#pragma unroll
  for (int m = 0; m < 4; ++m) {
#pragma unroll
    for (int j = 0; j < 4; ++j) {
      const size_t token = row0 + wm * 64 + m * 16 + lg * 4 + j;
      float* orow = OUT + token * 1024 + col0 + wn * 64 + lr;
#pragma unroll
      for (int n = 0; n < 4; ++n) orow[n * 16] = acc[m][n][j] + bias[n];
    }
  }
}

// ---------------------------------------------------------------------------
extern "C" void kernel_launch(void* const* d_in, const int* in_sizes, int n_in,
                              void* d_out, int out_size, void* d_ws, size_t ws_size,
                              hipStream_t stream) {
  const float* X    = (const float*)d_in[0];
  const float* Wqkv = (const float*)d_in[1];
  const float* Wp   = (const float*)d_in[2];
  const float* Pb   = (const float*)d_in[3];
  const float* Ct   = (const float*)d_in[4];
  const float* St   = (const float*)d_in[5];
  float* OUT = (float*)d_out;

  // ws: Xb 8MB | Wb 6MB | Wpb 2MB | qb 8MB | kb 8MB | vt 8MB | ab 8MB = 48MB
  unsigned short* Xb  = (unsigned short*)d_ws;
  unsigned short* Wb  = Xb + (size_t)4194304;
  unsigned short* Wpb = Wb + (size_t)3145728;
  unsigned short* qb  = Wpb + (size_t)1048576;
  unsigned short* kb  = qb + (size_t)4194304;
  unsigned short* vt  = kb + (size_t)4194304;
  unsigned short* ab  = vt + (size_t)4194304;

  k_convert<<<dim3(4096), 256, 0, stream>>>(X, Wqkv, Wp, Xb, Wb, Wpb);
  k_gemm_qkv<<<dim3(32, 24), 256, 0, stream>>>(Xb, Wb, Ct, St, qb, kb, vt);
  k_attn<<<dim3(1024), 256, 0, stream>>>(qb, kb, vt, ab);
  k_gemm_proj<<<dim3(32, 8), 256, 0, stream>>>(ab, Wpb, Pb, OUT);
}